// Round 14
// baseline (395.756 us; speedup 1.0000x reference)
//
#include <hip/hip_runtime.h>

typedef unsigned short u16;
typedef unsigned int u32;
typedef __attribute__((ext_vector_type(8))) short short8;
typedef __attribute__((ext_vector_type(4))) float f32x4;
typedef __attribute__((ext_vector_type(4))) u32 u32x4;

#define NPT 128
#define DIM 512
#define KT 48
#define KC 32
#define BPB 16               // batches per block (persistent pipeline)
#define NCH (BPB * 8)        // 16-row chunks per block

__device__ __forceinline__ u16 f2bf(float f) {
    unsigned u = __builtin_bit_cast(unsigned, f);
    return (u16)((u + 0x7FFFu + ((u >> 16) & 1u)) >> 16);
}

__device__ __forceinline__ u32 cvtpk(float lo, float hi) {
    u32 r;
    asm("v_cvt_pk_bf16_f32 %0, %1, %2" : "=v"(r) : "v"(lo), "v"(hi));
    return r;
}

// LDS-only barrier: drain this wave's LDS ops, then s_barrier. Does NOT
// drain vmcnt, so global loads/stores/DMAs stay in flight across it.
__device__ __forceinline__ void lds_barrier() {
    asm volatile("s_waitcnt lgkmcnt(0)" ::: "memory");
    __builtin_amdgcn_s_barrier();
}

// Chunk-handoff barrier: waits own DMA (vmcnt) + LDS ops, then s_barrier.
// After ALL waves pass, the previous chunk's DMA has fully landed.
__device__ __forceinline__ void chunk_barrier() {
    asm volatile("s_waitcnt vmcnt(0) lgkmcnt(0)" ::: "memory");
    __builtin_amdgcn_s_barrier();
}

// bank swizzle for cTsL (bf16, 1KB rows): 16B-granular XOR
__device__ __forceinline__ int swz(int n) {
    return ((n & 7) ^ (((n >> 3) & 1) << 2)) << 4;
}

// Fold BN into clusters: cTs[k][d] = bf16(clusters[d][k] * s_k), t[k] = b_k - rm_k*s_k
__global__ void prep_kernel(const float* __restrict__ clusters,
                            const float* __restrict__ bn_w,
                            const float* __restrict__ bn_b,
                            const float* __restrict__ bn_rm,
                            const float* __restrict__ bn_rv,
                            u16* __restrict__ cTs,
                            float* __restrict__ tvec) {
    const int k = blockIdx.x;
    const float s = bn_w[k] * rsqrtf(bn_rv[k] + 1e-5f);
    if (threadIdx.x == 0) tvec[k] = bn_b[k] - bn_rm[k] * s;
    for (int d = threadIdx.x; d < DIM; d += blockDim.x)
        cTs[k * DIM + d] = f2bf(clusters[d * KT + k] * s);
}

// DMA one 16-row fp32 chunk into bufF[c&1] via global_load_lds.
// LDS dest is LINEAR: wave slot s covers bytes [s*1024, s*1024+1024), lane l
// at +l*16. Content swizzle achieved by PRE-SWIZZLING the global source:
// LDS unit (half*64+l) of row r holds x[r][((half*64+l)^(r&7)) * 4 ..+4).
#define CH_ISSUE(c)                                                          \
    do {                                                                     \
        const float* gc_ = xblk + (size_t)(c) * (16 * DIM);                  \
        float* lb_ = &bufF[(c) & 1][0];                                      \
        _Pragma("unroll")                                                    \
        for (int i_ = 0; i_ < 4; ++i_) {                                     \
            const int slot_ = wave * 4 + i_;                                 \
            const int r_ = slot_ >> 1, half_ = slot_ & 1;                    \
            const int us_ = (half_ * 64 + lane) ^ (r_ & 7);                  \
            __builtin_amdgcn_global_load_lds(                                \
                (const __attribute__((address_space(1))) u32*)(gc_ + r_ * DIM + us_ * 4), \
                (__attribute__((address_space(3))) u32*)(lb_ + slot_ * 256), \
                16, 0, 0);                                                   \
        }                                                                    \
    } while (0)

__global__ __launch_bounds__(512)
void vlad_kernel(const float* __restrict__ x,
                 const float* __restrict__ c2,     // [512][32] fp32
                 const u16* __restrict__ cTs,      // [48][512] bf16
                 const float* __restrict__ tvec,   // [48]
                 float* __restrict__ out) {
    __shared__ __align__(16) float bufF[2][16 * DIM];  // 2 x 32 KB fp32 chunks
    __shared__ __align__(16) u16 cTsL[KT * DIM];       // 48 KB bf16, swizzled
    __shared__ __align__(16) u16 aT[KC][136];          // assignment^T
    __shared__ float asum_part[8][KC];
    __shared__ float colsq_part[8][KC];

    const int tid  = threadIdx.x;
    const int wave = tid >> 6;
    const int lane = tid & 63;
    const int lr   = lane & 15;
    const int lg   = lane >> 4;

    const int b0i = blockIdx.x * BPB;
    const float* xblk = x + (size_t)b0i * (NPT * DIM);

    const float t0 = tvec[lr], t1 = tvec[16 + lr], t2 = tvec[32 + lr];

    // ---- prologue: cTs -> LDS (swizzled bf16) ----
    #pragma unroll
    for (int i = 0; i < 6; ++i) {
        int idx = tid + i * 512;
        int k = idx >> 6, slot = idx & 63;
        u32x4 v = *(const u32x4*)(cTs + k * DIM + slot * 8);
        *(u32x4*)((char*)cTsL + k * 1024 + ((slot * 16) ^ swz(k))) = v;
    }
    // ---- prologue: DMA chunk 0 (lands before iteration 0's chunk_barrier) ----
    CH_ISSUE(0);

    for (int m = 0; m < BPB; ++m) {
        f32x4 acc0 = {0.f,0.f,0.f,0.f}, acc1 = {0.f,0.f,0.f,0.f}, acc2 = {0.f,0.f,0.f,0.f};
        short8 af2[4][4];   // phase-2 A-frags: [ns][dti]

        // ==== chunk loop. Iteration j (global chunk g): barrier (own DMA g
        //      landed + all waves' prev reads done) -> issue DMA g+1 -> read g.
        //      DMA g+1 streams across the entire iteration + tail. ====
        #pragma unroll
        for (int ns = 0; ns < 4; ++ns) {
            #pragma unroll
            for (int h = 0; h < 2; ++h) {
                const int j = ns * 2 + h;
                const int g = m * 8 + j;

                chunk_barrier();                    // chunk g ready everywhere
                if (g + 1 < NCH) { CH_ISSUE(g + 1); }   // post-barrier: prev readers done

                const float* bcur = &bufF[j & 1][0];

                // 1) extract phase-2 A-frags for chunk g (fp32 -> bf16)
                if ((lane >> 5) == h) {
                    const int nb = (lg & 1) * 8;
                    #pragma unroll
                    for (int dti = 0; dti < 4; ++dti) {
                        const int d = wave * 64 + dti * 16 + lr;  // float col
                        const int u = d >> 2, o = d & 3;
                        float f[8];
                        #pragma unroll
                        for (int jj = 0; jj < 8; ++jj) {
                            const int rr = nb + jj;
                            f[jj] = bcur[rr * DIM + ((u ^ (rr & 7)) * 4 + o)];
                        }
                        u32x4 w;
                        w[0] = cvtpk(f[0], f[1]); w[1] = cvtpk(f[2], f[3]);
                        w[2] = cvtpk(f[4], f[5]); w[3] = cvtpk(f[6], f[7]);
                        af2[ns][dti] = __builtin_bit_cast(short8, w);
                    }
                }

                // 2) phase 1: wave j computes logits for its 16 rows
                if (wave == j) {
                    const float* xrow = bcur + lr * DIM;
                    const int xsw = lr & 7;
                    const char* cb0 = (const char*)cTsL + lr * 1024;
                    const char* cb1 = (const char*)cTsL + (16 + lr) * 1024;
                    const char* cb2 = (const char*)cTsL + (32 + lr) * 1024;
                    const int s0 = swz(lr), s1 = swz(16 + lr), s2 = swz(32 + lr);
                    #pragma unroll 4
                    for (int step = 0; step < 16; ++step) {
                        const int u0 = step * 8 + lg * 2;         // 16B unit
                        f32x4 xa = *(const f32x4*)(xrow + (u0 ^ xsw) * 4);
                        f32x4 xb = *(const f32x4*)(xrow + ((u0 + 1) ^ xsw) * 4);
                        u32x4 aw;
                        aw[0] = cvtpk(xa[0], xa[1]); aw[1] = cvtpk(xa[2], xa[3]);
                        aw[2] = cvtpk(xb[0], xb[1]); aw[3] = cvtpk(xb[2], xb[3]);
                        short8 af = __builtin_bit_cast(short8, aw);
                        const int off = step * 64 + lg * 16;
                        short8 bb0 = *(const short8*)(cb0 + (off ^ s0));
                        short8 bb1 = *(const short8*)(cb1 + (off ^ s1));
                        short8 bb2 = *(const short8*)(cb2 + (off ^ s2));
                        acc0 = __builtin_amdgcn_mfma_f32_16x16x32_bf16(af, bb0, acc0, 0, 0, 0);
                        acc1 = __builtin_amdgcn_mfma_f32_16x16x32_bf16(af, bb1, acc1, 0, 0, 0);
                        acc2 = __builtin_amdgcn_mfma_f32_16x16x32_bf16(af, bb2, acc2, 0, 0, 0);
                    }
                }
                // no trailing barrier: next iteration's chunk_barrier handles it
            }
        }

        // ---- softmax over 48, keep 32; aT bf16; per-wave asum partials ----
        {
            float a0[4], a1[4];
            #pragma unroll
            for (int r = 0; r < 4; ++r) {
                float l0 = acc0[r] + t0, l1 = acc1[r] + t1, l2 = acc2[r] + t2;
                float mx = fmaxf(fmaxf(l0, l1), l2);
                #pragma unroll
                for (int o = 1; o < 16; o <<= 1) mx = fmaxf(mx, __shfl_xor(mx, o));
                float e0 = __expf(l0 - mx), e1 = __expf(l1 - mx), e2 = __expf(l2 - mx);
                float s = e0 + e1 + e2;
                #pragma unroll
                for (int o = 1; o < 16; o <<= 1) s += __shfl_xor(s, o);
                float inv = 1.0f / s;
                a0[r] = e0 * inv; a1[r] = e1 * inv;
            }
            float p0 = 0.f, p1 = 0.f;
            #pragma unroll
            for (int r = 0; r < 4; ++r) {
                int n = wave * 16 + lg * 4 + r;
                aT[lr][n]      = f2bf(a0[r]);
                aT[16 + lr][n] = f2bf(a1[r]);
                p0 += a0[r]; p1 += a1[r];
            }
            p0 += __shfl_xor(p0, 16); p0 += __shfl_xor(p0, 32);
            p1 += __shfl_xor(p1, 16); p1 += __shfl_xor(p1, 32);
            if (lane < 16) { asum_part[wave][lane] = p0; asum_part[wave][16 + lane] = p1; }
        }
        lds_barrier();   // b1: aT + asum_part ready (DMA for next chunk stays in flight)

        // ---- phase 2: pure register A (af2) x aT B-frags ----
        f32x4 vacc[4][2];
        #pragma unroll
        for (int i = 0; i < 4; ++i) {
            vacc[i][0] = (f32x4){0.f,0.f,0.f,0.f};
            vacc[i][1] = (f32x4){0.f,0.f,0.f,0.f};
        }
        #pragma unroll
        for (int ns = 0; ns < 4; ++ns) {
            short8 bf0 = *(const short8*)(&aT[lr][ns * 32 + lg * 8]);
            short8 bf1 = *(const short8*)(&aT[16 + lr][ns * 32 + lg * 8]);
            #pragma unroll
            for (int dti = 0; dti < 4; ++dti) {
                vacc[dti][0] = __builtin_amdgcn_mfma_f32_16x16x32_bf16(af2[ns][dti], bf0, vacc[dti][0], 0, 0, 0);
                vacc[dti][1] = __builtin_amdgcn_mfma_f32_16x16x32_bf16(af2[ns][dti], bf1, vacc[dti][1], 0, 0, 0);
            }
        }

        // ---- epilogue ----
        float as0 = 0.f, as1 = 0.f;
        #pragma unroll
        for (int w2 = 0; w2 < 8; ++w2) {
            as0 += asum_part[w2][lr];
            as1 += asum_part[w2][16 + lr];
        }
        float cs0 = 0.f, cs1 = 0.f;
        #pragma unroll
        for (int dti = 0; dti < 4; ++dti) {
            #pragma unroll
            for (int r = 0; r < 4; ++r) {
                int d = (wave * 4 + dti) * 16 + lg * 4 + r;
                float v0 = vacc[dti][0][r] - as0 * c2[d * KC + lr];
                float v1 = vacc[dti][1][r] - as1 * c2[d * KC + 16 + lr];
                vacc[dti][0][r] = v0; vacc[dti][1][r] = v1;
                cs0 += v0 * v0; cs1 += v1 * v1;
            }
        }
        cs0 += __shfl_xor(cs0, 16); cs0 += __shfl_xor(cs0, 32);
        cs1 += __shfl_xor(cs1, 16); cs1 += __shfl_xor(cs1, 32);
        if (lane < 16) { colsq_part[wave][lane] = cs0; colsq_part[wave][16 + lane] = cs1; }
        lds_barrier();   // colsq-b
        float sq0 = 0.f, sq1 = 0.f;
        #pragma unroll
        for (int w2 = 0; w2 < 8; ++w2) {
            sq0 += colsq_part[w2][lr];
            sq1 += colsq_part[w2][16 + lr];
        }
        float cn0 = sqrtf(sq0), cn1 = sqrtf(sq1);
        float s10 = 1.0f / fmaxf(cn0, 1e-12f);
        float s11 = 1.0f / fmaxf(cn1, 1e-12f);
        float c10 = cn0 * s10, c11 = cn1 * s11;
        float tot = c10 * c10 + c11 * c11;
        #pragma unroll
        for (int o = 1; o < 16; o <<= 1) tot += __shfl_xor(tot, o);
        float gs = 1.0f / fmaxf(sqrtf(tot), 1e-12f);
        float sk0 = s10 * gs, sk1 = s11 * gs;
        {
            float* ob = out + (size_t)(b0i + m) * (DIM * KC);
            #pragma unroll
            for (int dti = 0; dti < 4; ++dti) {
                #pragma unroll
                for (int r = 0; r < 4; ++r) {
                    int d = (wave * 4 + dti) * 16 + lg * 4 + r;
                    ob[d * KC + lr]      = vacc[dti][0][r] * sk0;
                    ob[d * KC + 16 + lr] = vacc[dti][1][r] * sk1;
                }
            }
        }
        // DMA for next batch's chunk 0 (issued at j=7) streamed across this
        // tail; next chunk loop's first chunk_barrier waits for it.
    }
}

extern "C" void kernel_launch(void* const* d_in, const int* in_sizes, int n_in,
                              void* d_out, int out_size, void* d_ws, size_t ws_size,
                              hipStream_t stream) {
    const float* x        = (const float*)d_in[0];
    const float* clusters = (const float*)d_in[1];
    const float* bn_w     = (const float*)d_in[2];
    const float* bn_b     = (const float*)d_in[3];
    const float* bn_rm    = (const float*)d_in[4];
    const float* bn_rv    = (const float*)d_in[5];
    const float* c2       = (const float*)d_in[6];
    float* out = (float*)d_out;

    u16*   cTs  = (u16*)d_ws;
    float* tvec = (float*)((char*)d_ws + KT * DIM * sizeof(u16));

    const int B = in_sizes[0] / (NPT * DIM);

    prep_kernel<<<KT, 256, 0, stream>>>(clusters, bn_w, bn_b, bn_rm, bn_rv, cTs, tvec);
    vlad_kernel<<<B / BPB, 512, 0, stream>>>(x, c2, cTs, tvec, out);
}